// Round 1
// baseline (468.064 us; speedup 1.0000x reference)
//
#include <hip/hip_runtime.h>

// SimilarityAttentionFusion reduces to an identity copy:
// DIST_PENALTY=770000 >> score dynamic range (scores ~ N(0,1) after /sqrt(768)),
// so softmax(scores - 770000*|i-j|) is bitwise the identity matrix in f32/f64
// (off-diagonal exponents ~ -7.7e5 underflow exp() to exactly 0.0).
// => out[b,q,:] = 1.0 * global_embedding[b,q,:]  (bit-exact).
// Structural floor: read 242 MB + write 242 MB of HBM traffic (~77 us @ 6.3 TB/s).

__global__ __launch_bounds__(256) void sim_attn_copy_kernel(
    const float4* __restrict__ src, float4* __restrict__ dst, long long n4) {
    long long i = (long long)blockIdx.x * blockDim.x + threadIdx.x;
    if (i < n4) {
        dst[i] = src[i];
    }
}

extern "C" void kernel_launch(void* const* d_in, const int* in_sizes, int n_in,
                              void* d_out, int out_size, void* d_ws, size_t ws_size,
                              hipStream_t stream) {
    // d_in[0] = global_embedding [B=1024, L=77, D=768] f32 (dict order; it is K=V and
    // the exact output). d_in[1] = local_embedding (unused: attn is identity).
    const float4* src = (const float4*)d_in[0];
    float4* dst = (float4*)d_out;

    long long n4 = (long long)out_size / 4;  // 60,555,264 / 4 = 15,138,816 (D=768 % 4 == 0)
    int block = 256;
    long long grid = (n4 + block - 1) / block;  // 59,136 blocks
    sim_attn_copy_kernel<<<(dim3)(unsigned)grid, block, 0, stream>>>(src, dst, n4);
}

// Round 3
// 462.817 us; speedup vs baseline: 1.0113x; 1.0113x over previous
//
#include <hip/hip_runtime.h>

// SimilarityAttentionFusion reduces to an identity copy (see R0 analysis):
// softmax(scores - 770000*|i-j|) is bitwise the identity matrix (off-diagonal
// exponents ~ -7.7e5 underflow exp() to exactly 0.0), so
// out[b,q,:] = global_embedding[b,q,:] bit-exact.
//
// R1: plain float4 copy passed, absmax=0, kernel <148 us (below top-5 cutoff);
// bench dur_us=468 dominated by harness poison-fill (969 MB @ 148 us) + input
// restores. Floor for our portion: 242+242 MB @ ~6.3 TB/s ~= 77 us.
// R2 fix: __builtin_nontemporal_* needs a native clang vector type, not
// HIP_vector_type — use ext_vector_type(4) float.

typedef float v4f __attribute__((ext_vector_type(4)));  // 16 B, 16-B aligned

__global__ __launch_bounds__(256) void sim_attn_copy_kernel(
    const v4f* __restrict__ src, v4f* __restrict__ dst, long long n4) {
    long long i = (long long)blockIdx.x * blockDim.x + threadIdx.x;
    if (i < n4) {
        v4f v = __builtin_nontemporal_load(&src[i]);   // global_load_dwordx4 ... nt
        __builtin_nontemporal_store(v, &dst[i]);       // global_store_dwordx4 ... nt
    }
}

extern "C" void kernel_launch(void* const* d_in, const int* in_sizes, int n_in,
                              void* d_out, int out_size, void* d_ws, size_t ws_size,
                              hipStream_t stream) {
    // d_in[0] = global_embedding [1024, 77, 768] f32 — equals the output exactly.
    // d_in[1] = local_embedding — unused (attention matrix is identity).
    const v4f* src = (const v4f*)d_in[0];
    v4f* dst = (v4f*)d_out;

    long long n4 = (long long)out_size / 4;  // 15,138,816 float4s; divides 256 exactly
    int block = 256;
    long long grid = (n4 + block - 1) / block;  // 59,136 blocks
    sim_attn_copy_kernel<<<(dim3)(unsigned)grid, block, 0, stream>>>(src, dst, n4);
}